// Round 21
// baseline (120.483 us; speedup 1.0000x reference)
//
#include <hip/hip_runtime.h>
#include <hip/hip_bf16.h>
#include <hip/hip_fp8.h>

#define S_ 1024
#define D_ 128
#define V_ 100000
#define VSTRIPS_ 3264   // 32-row v-strips; 3125 valid, 139 zero pads (51/phase)
#define NPHASE_ 64      // 64 phases x 51 strips = 3264
#define N_ 4096
#define PADROWS_ 4448.0f   // (3264*32 - 100000) pad columns, each exp2(0)=1

typedef __attribute__((ext_vector_type(4))) float f32x4;
typedef __attribute__((ext_vector_type(4))) int   i32x4;
typedef __attribute__((ext_vector_type(8))) int   i32x8;

#define LOG2E_ 1.4426950408889634f
#define LN2_   0.6931471805599453f

__device__ __forceinline__ float exp2_fast(float x) {
#if __has_builtin(__builtin_amdgcn_exp2f)
    return __builtin_amdgcn_exp2f(x);
#else
    return exp2f(x);
#endif
}

__device__ __forceinline__ unsigned char to_fp8(float x) {
    __hip_fp8_e4m3 t(x);
    return (unsigned char)t.__x;
}
__device__ __forceinline__ float from_fp8(unsigned char b) {
    __hip_fp8_e4m3 t; t.__x = (__hip_fp8_storage_t)b;
    return (float)t;
}

// ---- kernel 1: prep = knorm (fragment-major fp8 Kn) + qnorm (row-major fp8 Qn) ----
// Kn strip layout (CONTIGUOUS 32B per MFMA lane): strip = 4KB,
//   element (r local, k): addr = (r>>4)*2048 + ((k>>5)*16 + (r&15))*32 + (k&31)
__global__ void prep_kernel(const float* __restrict__ K, const float* __restrict__ Q,
                            const int* __restrict__ loc,
                            char* __restrict__ Kn, char* __restrict__ Qn,
                            float* __restrict__ Ssum) {
    __shared__ char sm[4096];
    const int bid = blockIdx.x;
    const int tid = threadIdx.x;
    const int lane = tid & 63;
    const int wvv = tid >> 6;
    if (bid < VSTRIPS_) {                      // ---- K strip ----
        char* dst = Kn + (size_t)bid * 4096;
        if (bid >= 3125) {                     // zero pad strip: fp8 0x00 = 0.0
            *(f32x4*)(dst + tid * 16) = (f32x4){0.f, 0.f, 0.f, 0.f};
            return;
        }
        #pragma unroll
        for (int i = 0; i < 8; ++i) {
            int r = wvv * 8 + i;
            float2 v = ((const float2*)(K + ((size_t)bid * 32 + r) * D_))[lane];
            float ss = v.x * v.x + v.y * v.y;
            #pragma unroll
            for (int off = 32; off; off >>= 1) ss += __shfl_xor(ss, off);
            float rn = rsqrtf(ss);
            unsigned short pk = (unsigned short)to_fp8(v.x * rn)
                              | ((unsigned short)to_fp8(v.y * rn) << 8);
            int addr = ((r >> 4) << 11) + (((lane >> 4) * 16 + (r & 15)) << 5)
                     + ((lane & 15) << 1);
            *(unsigned short*)(sm + addr) = pk;
        }
        __syncthreads();
        *(f32x4*)(dst + tid * 16) = *(const f32x4*)(sm + tid * 16);
    } else {                                   // ---- Q rows (4 per block) ----
        int w = (bid - VSTRIPS_) * 4 + wvv;
        if (lane == 0) Ssum[w] = 0.f;
        int b = loc[2 * w], s = loc[2 * w + 1];
        float2 v = ((const float2*)(Q + ((size_t)b * S_ + (size_t)s) * D_))[lane];
        float ss = v.x * v.x + v.y * v.y;
        #pragma unroll
        for (int off = 32; off; off >>= 1) ss += __shfl_xor(ss, off);
        float rn = rsqrtf(ss) * LOG2E_;        // exp2 domain
        unsigned short pk = (unsigned short)to_fp8(v.x * rn)
                          | ((unsigned short)to_fp8(v.y * rn) << 8);
        *(unsigned short*)(Qn + (size_t)w * 128 + 2 * lane) = pk;
    }
}

// ---- kernel 2: main  sum_v exp2(q . k_v)  -- MX-fp8 K=128, NO LDS, NO BARRIERS ----
// R18 structure + 2-strip-deep register prefetch (3 rotating buffer sets,
// load-use distance ~2 compute phases to cover L2-under-load latency).
// Wave: 64q x 32v (m=4, nn=2 -> 8 MFMA + 32 exp2 per strip).
__global__ __launch_bounds__(256, 2) void ce_main(
    const char* __restrict__ Qn,
    const char* __restrict__ Kn,
    float* __restrict__ Ssum)
{
    const int tid  = threadIdx.x;
    const int lane = tid & 63;
    const int wv   = tid >> 6;
    const int r0   = lane & 15;
    const int hi   = lane >> 4;          // 0..3

    // grid (16,64): XCD owns 8 whole phase-groups (all 16 q-blocks of each)
    const int fid   = blockIdx.y * 16 + blockIdx.x;
    const int xcd   = fid & 7;
    const int idx   = fid >> 3;              // 0..127
    const int phase = xcd * 8 + (idx >> 4);  // 0..63
    const int qb    = idx & 15;              // 0..15 (256 q-rows each)

    // ---- Q fragments (fp8) -> registers: row=lane&15, k-bytes (lane>>4)*32 ----
    i32x8 afr[4];
    {
        const char* qsrc = Qn + ((size_t)qb * 256 + wv * 64 + r0) * 128 + (hi << 5);
        #pragma unroll
        for (int m = 0; m < 4; ++m)
            afr[m] = *(const i32x8*)(qsrc + m * 2048);
    }

    // strip j (0..50) at phase + NPHASE_*j; operand = base + lane*32 (+2048 nn=1)
    const char* kvbase = Kn + (size_t)phase * 4096 + (lane << 5);

#define LOADSET(B0, B1, j) do {                                              \
        const char* p = kvbase + (size_t)(j) * (4096 * NPHASE_);             \
        B0 = *(const i32x8*)(p);                                             \
        B1 = *(const i32x8*)(p + 2048);                                      \
    } while (0)

#define COMPUTE(B0, B1, ACC) do {                                            \
        _Pragma("unroll")                                                    \
        for (int m = 0; m < 4; ++m) {                                        \
            ACC[m][0] = __builtin_amdgcn_mfma_scale_f32_16x16x128_f8f6f4(    \
                afr[m], B0, fz, 0, 0, 0, 127, 0, 127);                       \
            ACC[m][1] = __builtin_amdgcn_mfma_scale_f32_16x16x128_f8f6f4(    \
                afr[m], B1, fz, 0, 0, 0, 127, 0, 127);                       \
        }                                                                    \
    } while (0)

#define EXP2S(ACC) do {                                                      \
        _Pragma("unroll")                                                    \
        for (int m = 0; m < 4; ++m)                                          \
            _Pragma("unroll")                                                \
            for (int q = 0; q < 4; ++q)                                      \
                psum[m][q] += exp2_fast(ACC[m][0][q]) + exp2_fast(ACC[m][1][q]); \
    } while (0)

    float psum[4][4];
    #pragma unroll
    for (int m = 0; m < 4; ++m)
        #pragma unroll
        for (int q = 0; q < 4; ++q) psum[m][q] = 0.f;

    const f32x4 fz = {0.f, 0.f, 0.f, 0.f};
    f32x4 accE[4][2], accO[4][2];
    #pragma unroll
    for (int m = 0; m < 4; ++m)
        #pragma unroll
        for (int nn = 0; nn < 2; ++nn)
            accO[m][nn] = (f32x4){-16384.f, -16384.f, -16384.f, -16384.f}; // exp2 -> 0

    i32x8 A0, A1, B0, B1, C0, C1;
    LOADSET(A0, A1, 0);
    LOADSET(B0, B1, 1);
    #pragma unroll 1
    for (int j = 0; j < 48; j += 6) {        // strips j..j+5; loads 2 ahead
        LOADSET(C0, C1, j + 2); EXP2S(accO); COMPUTE(A0, A1, accE);   // strip j
        LOADSET(A0, A1, j + 3); EXP2S(accE); COMPUTE(B0, B1, accO);   // j+1
        LOADSET(B0, B1, j + 4); EXP2S(accO); COMPUTE(C0, C1, accE);   // j+2
        LOADSET(C0, C1, j + 5); EXP2S(accE); COMPUTE(A0, A1, accO);   // j+3
        LOADSET(A0, A1, j + 6); EXP2S(accO); COMPUTE(B0, B1, accE);   // j+4
        LOADSET(B0, B1, j + 7); EXP2S(accE); COMPUTE(C0, C1, accO);   // j+5
    }
    // after loop: A = strip 48, B = strip 49 already loaded
    LOADSET(C0, C1, 50);
    EXP2S(accO); COMPUTE(A0, A1, accE);      // strip 48 (exps 47)
    EXP2S(accE); COMPUTE(B0, B1, accO);      // strip 49 (exps 48)
    EXP2S(accO); COMPUTE(C0, C1, accE);      // strip 50 (exps 49)
    EXP2S(accE);                             // exps strip 50

#undef LOADSET
#undef COMPUTE
#undef EXP2S

    // C/D 16x16: col=lane&15 (v), row=hi*4+reg (q). Reduce over v-cols, atomics.
    #pragma unroll
    for (int m = 0; m < 4; ++m) {
        #pragma unroll
        for (int q = 0; q < 4; ++q) {
            float v = psum[m][q];
            v += __shfl_xor(v, 1);
            v += __shfl_xor(v, 2);
            v += __shfl_xor(v, 4);
            v += __shfl_xor(v, 8);
            if (r0 == 0) {
                int row = qb * 256 + wv * 64 + m * 16 + hi * 4 + q;
                atomicAdd(&Ssum[row], v);
            }
        }
    }
}

// ---- kernel 3: per-row term = log(S - PADROWS) - true_logit ----
// Kn element (r=lab&31, k=2*lane): addr = (lab>>5)*4096 + ((lab>>4)&1)*2048
//   + ((lane>>4)*16 + (lab&15))*32 + 2*(lane&15)
__global__ void term_kernel(const char* __restrict__ Qn,
                            const char* __restrict__ Kn,
                            const int* __restrict__ labels,
                            const float* __restrict__ Ssum,
                            float* __restrict__ T) {
    int w = (blockIdx.x * blockDim.x + threadIdx.x) >> 6;
    int lane = threadIdx.x & 63;
    if (w >= N_) return;
    int lab = labels[w];
    const unsigned char* qp = (const unsigned char*)(Qn + (size_t)w * 128 + 2 * lane);
    const unsigned char* kp = (const unsigned char*)(Kn
                      + ((size_t)(lab >> 5)) * 4096 + (((lab >> 4) & 1) << 11)
                      + (((lane >> 4) * 16 + (lab & 15)) << 5) + ((lane & 15) << 1));
    float d = from_fp8(qp[0]) * from_fp8(kp[0])
            + from_fp8(qp[1]) * from_fp8(kp[1]);
    #pragma unroll
    for (int off = 32; off; off >>= 1) d += __shfl_xor(d, off);
    if (lane == 0) T[w] = logf(Ssum[w] - PADROWS_) - d * LN2_;
}

// ---- kernel 4: mean over N ----
__global__ void reduce_kernel(const float* __restrict__ T, float* __restrict__ out) {
    __shared__ float sm[4];
    float s = 0.f;
    for (int i = threadIdx.x; i < N_; i += 256) s += T[i];
    #pragma unroll
    for (int off = 32; off; off >>= 1) s += __shfl_xor(s, off);
    if ((threadIdx.x & 63) == 0) sm[threadIdx.x >> 6] = s;
    __syncthreads();
    if (threadIdx.x == 0) out[0] = (sm[0] + sm[1] + sm[2] + sm[3]) * (1.0f / (float)N_);
}

extern "C" void kernel_launch(void* const* d_in, const int* in_sizes, int n_in,
                              void* d_out, int out_size, void* d_ws, size_t ws_size,
                              hipStream_t stream) {
    (void)in_sizes; (void)n_in; (void)out_size; (void)ws_size;
    const float* Q   = (const float*)d_in[0];
    const float* K   = (const float*)d_in[1];
    const int* loc   = (const int*)d_in[2];
    const int* labels= (const int*)d_in[3];
    float* out = (float*)d_out;

    char* ws = (char*)d_ws;
    char* Kn    = ws;                                   // 3264*4096 = 13,369,344 B
    char* Qn    = ws + 13369344;                        // N_*128    =     524,288 B
    float* Ssum = (float*)(ws + 13369344 + 524288);     // N_*4
    float* T    = Ssum + N_;                            // N_*4

    prep_kernel<<<VSTRIPS_ + N_ / 4, 256, 0, stream>>>(K, Q, loc, Kn, Qn, Ssum);
    ce_main<<<dim3(16, NPHASE_), 256, 0, stream>>>(Qn, Kn, Ssum);
    term_kernel<<<N_ / 4, 256, 0, stream>>>(Qn, Kn, labels, Ssum, T);
    reduce_kernel<<<1, 256, 0, stream>>>(T, out);
}

// Round 22
// 78.499 us; speedup vs baseline: 1.5348x; 1.5348x over previous
//
#include <hip/hip_runtime.h>
#include <hip/hip_bf16.h>
#include <hip/hip_fp8.h>

#define S_ 1024
#define D_ 128
#define V_ 100000
#define VSTRIPS_ 3136   // 32-row v-strips; 3125 valid (=100000), 11 zero pads
#define NPHASE_ 64      // 64 phases x 49 strips = 3136
#define N_ 4096
#define PADROWS_ 352.0f

typedef __attribute__((ext_vector_type(4))) float f32x4;
typedef __attribute__((ext_vector_type(4))) int   i32x4;
typedef __attribute__((ext_vector_type(8))) int   i32x8;

#define LOG2E_ 1.4426950408889634f
#define LN2_   0.6931471805599453f

__device__ __forceinline__ float exp2_fast(float x) {
#if __has_builtin(__builtin_amdgcn_exp2f)
    return __builtin_amdgcn_exp2f(x);
#else
    return exp2f(x);
#endif
}

__device__ __forceinline__ unsigned char to_fp8(float x) {
    __hip_fp8_e4m3 t(x);
    return (unsigned char)t.__x;
}
__device__ __forceinline__ float from_fp8(unsigned char b) {
    __hip_fp8_e4m3 t; t.__x = (__hip_fp8_storage_t)b;
    return (float)t;
}

// ---- kernel 1: prep = knorm (fragment-major fp8 Kn) + qnorm (row-major fp8 Qn) ----
// Kn strip layout (CONTIGUOUS 32B per MFMA lane): strip = 4KB,
//   element (r local, k): addr = (r>>4)*2048 + ((k>>5)*16 + (r&15))*32 + (k&31)
// -> B-operand read for nn-half: addr = nn*2048 + lane*32 + [0..31] (one i32x8).
__global__ void prep_kernel(const float* __restrict__ K, const float* __restrict__ Q,
                            const int* __restrict__ loc,
                            char* __restrict__ Kn, char* __restrict__ Qn,
                            float* __restrict__ Ssum) {
    __shared__ char sm[4096];
    const int bid = blockIdx.x;
    const int tid = threadIdx.x;
    const int lane = tid & 63;
    const int wvv = tid >> 6;
    if (bid < VSTRIPS_) {                      // ---- K strip ----
        char* dst = Kn + (size_t)bid * 4096;
        if (bid >= 3125) {                     // zero pad strip: fp8 0x00 = 0.0
            *(f32x4*)(dst + tid * 16) = (f32x4){0.f, 0.f, 0.f, 0.f};
            return;
        }
        #pragma unroll
        for (int i = 0; i < 8; ++i) {
            int r = wvv * 8 + i;
            float2 v = ((const float2*)(K + ((size_t)bid * 32 + r) * D_))[lane];
            float ss = v.x * v.x + v.y * v.y;
            #pragma unroll
            for (int off = 32; off; off >>= 1) ss += __shfl_xor(ss, off);
            float rn = rsqrtf(ss);
            unsigned short pk = (unsigned short)to_fp8(v.x * rn)
                              | ((unsigned short)to_fp8(v.y * rn) << 8);
            int addr = ((r >> 4) << 11) + (((lane >> 4) * 16 + (r & 15)) << 5)
                     + ((lane & 15) << 1);
            *(unsigned short*)(sm + addr) = pk;
        }
        __syncthreads();
        *(f32x4*)(dst + tid * 16) = *(const f32x4*)(sm + tid * 16);
    } else {                                   // ---- Q rows (4 per block) ----
        int w = (bid - VSTRIPS_) * 4 + wvv;
        if (lane == 0) Ssum[w] = 0.f;
        int b = loc[2 * w], s = loc[2 * w + 1];
        float2 v = ((const float2*)(Q + ((size_t)b * S_ + (size_t)s) * D_))[lane];
        float ss = v.x * v.x + v.y * v.y;
        #pragma unroll
        for (int off = 32; off; off >>= 1) ss += __shfl_xor(ss, off);
        float rn = rsqrtf(ss) * LOG2E_;        // exp2 domain
        unsigned short pk = (unsigned short)to_fp8(v.x * rn)
                          | ((unsigned short)to_fp8(v.y * rn) << 8);
        *(unsigned short*)(Qn + (size_t)w * 128 + 2 * lane) = pk;
    }
}

// ---- kernel 2: main  sum_v exp2(q . k_v)  -- MX-fp8 K=128, NO LDS, NO BARRIERS ----
// mfma_scale_f32_16x16x128_f8f6f4, scales=127 (E8M0 2^0) -> plain e4m3 matmul.
// Wave: 64q x 32v (m=4, nn=2 -> 8 MFMA + 32 exp2 per strip).
// Register double-buffer one strip ahead (2 sets -- 3 sets spill, R21).
__global__ __launch_bounds__(256, 2) void ce_main(
    const char* __restrict__ Qn,
    const char* __restrict__ Kn,
    float* __restrict__ Ssum)
{
    const int tid  = threadIdx.x;
    const int lane = tid & 63;
    const int wv   = tid >> 6;
    const int r0   = lane & 15;
    const int hi   = lane >> 4;          // 0..3

    // grid (16,64): XCD owns 8 whole phase-groups (all 16 q-blocks of each)
    const int fid   = blockIdx.y * 16 + blockIdx.x;
    const int xcd   = fid & 7;
    const int idx   = fid >> 3;              // 0..127
    const int phase = xcd * 8 + (idx >> 4);  // 0..63
    const int qb    = idx & 15;              // 0..15 (256 q-rows each)

    // ---- Q fragments (fp8) -> registers: row=lane&15, k-bytes (lane>>4)*32 ----
    i32x8 afr[4];
    {
        const char* qsrc = Qn + ((size_t)qb * 256 + wv * 64 + r0) * 128 + (hi << 5);
        #pragma unroll
        for (int m = 0; m < 4; ++m)
            afr[m] = *(const i32x8*)(qsrc + m * 2048);
    }

    // strip j (0..48) at phase + NPHASE_*j; operand = base + lane*32 (+2048 for nn=1)
    const char* kvbase = Kn + (size_t)phase * 4096 + (lane << 5);

#define LOADSET(B0, B1, j) do {                                              \
        const char* p = kvbase + (size_t)(j) * (4096 * NPHASE_);             \
        B0 = *(const i32x8*)(p);                                             \
        B1 = *(const i32x8*)(p + 2048);                                      \
    } while (0)

#define COMPUTE(B0, B1, ACC) do {                                            \
        _Pragma("unroll")                                                    \
        for (int m = 0; m < 4; ++m) {                                        \
            ACC[m][0] = __builtin_amdgcn_mfma_scale_f32_16x16x128_f8f6f4(    \
                afr[m], B0, fz, 0, 0, 0, 127, 0, 127);                       \
            ACC[m][1] = __builtin_amdgcn_mfma_scale_f32_16x16x128_f8f6f4(    \
                afr[m], B1, fz, 0, 0, 0, 127, 0, 127);                       \
        }                                                                    \
    } while (0)

#define EXP2S(ACC) do {                                                      \
        _Pragma("unroll")                                                    \
        for (int m = 0; m < 4; ++m)                                          \
            _Pragma("unroll")                                                \
            for (int q = 0; q < 4; ++q)                                      \
                psum[m][q] += exp2_fast(ACC[m][0][q]) + exp2_fast(ACC[m][1][q]); \
    } while (0)

    float psum[4][4];
    #pragma unroll
    for (int m = 0; m < 4; ++m)
        #pragma unroll
        for (int q = 0; q < 4; ++q) psum[m][q] = 0.f;

    const f32x4 fz = {0.f, 0.f, 0.f, 0.f};
    f32x4 accE[4][2], accO[4][2];
    #pragma unroll
    for (int m = 0; m < 4; ++m)
        #pragma unroll
        for (int nn = 0; nn < 2; ++nn)
            accO[m][nn] = (f32x4){-16384.f, -16384.f, -16384.f, -16384.f}; // exp2 -> 0

    i32x8 RA0, RA1, RB0, RB1;
    LOADSET(RA0, RA1, 0);
    #pragma unroll 1
    for (int j = 0; j < 48; j += 2) {
        LOADSET(RB0, RB1, j + 1);        // prefetch next strip
        EXP2S(accO);                     // strip j-1 exp2 under load latency
        COMPUTE(RA0, RA1, accE);         // strip j
        LOADSET(RA0, RA1, j + 2);        // j+2 <= 48: valid
        EXP2S(accE);                     // strip j
        COMPUTE(RB0, RB1, accO);         // strip j+1
    }
    // epilogue: strip 48 (already in RA)
    EXP2S(accO);                         // strip 47
    COMPUTE(RA0, RA1, accE);             // strip 48
    EXP2S(accE);                         // strip 48

#undef LOADSET
#undef COMPUTE
#undef EXP2S

    // C/D 16x16: col=lane&15 (v), row=hi*4+reg (q). Reduce over v-cols, atomics.
    #pragma unroll
    for (int m = 0; m < 4; ++m) {
        #pragma unroll
        for (int q = 0; q < 4; ++q) {
            float v = psum[m][q];
            v += __shfl_xor(v, 1);
            v += __shfl_xor(v, 2);
            v += __shfl_xor(v, 4);
            v += __shfl_xor(v, 8);
            if (r0 == 0) {
                int row = qb * 256 + wv * 64 + m * 16 + hi * 4 + q;
                atomicAdd(&Ssum[row], v);
            }
        }
    }
}

// ---- kernel 3: per-row term = log(S - PADROWS) - true_logit ----
// Kn element (r=lab&31, k=2*lane): addr = (lab>>5)*4096 + ((lab>>4)&1)*2048
//   + ((lane>>4)*16 + (lab&15))*32 + 2*(lane&15)
__global__ void term_kernel(const char* __restrict__ Qn,
                            const char* __restrict__ Kn,
                            const int* __restrict__ labels,
                            const float* __restrict__ Ssum,
                            float* __restrict__ T) {
    int w = (blockIdx.x * blockDim.x + threadIdx.x) >> 6;
    int lane = threadIdx.x & 63;
    if (w >= N_) return;
    int lab = labels[w];
    const unsigned char* qp = (const unsigned char*)(Qn + (size_t)w * 128 + 2 * lane);
    const unsigned char* kp = (const unsigned char*)(Kn
                      + ((size_t)(lab >> 5)) * 4096 + (((lab >> 4) & 1) << 11)
                      + (((lane >> 4) * 16 + (lab & 15)) << 5) + ((lane & 15) << 1));
    float d = from_fp8(qp[0]) * from_fp8(kp[0])
            + from_fp8(qp[1]) * from_fp8(kp[1]);
    #pragma unroll
    for (int off = 32; off; off >>= 1) d += __shfl_xor(d, off);
    if (lane == 0) T[w] = logf(Ssum[w] - PADROWS_) - d * LN2_;
}

// ---- kernel 4: mean over N ----
__global__ void reduce_kernel(const float* __restrict__ T, float* __restrict__ out) {
    __shared__ float sm[4];
    float s = 0.f;
    for (int i = threadIdx.x; i < N_; i += 256) s += T[i];
    #pragma unroll
    for (int off = 32; off; off >>= 1) s += __shfl_xor(s, off);
    if ((threadIdx.x & 63) == 0) sm[threadIdx.x >> 6] = s;
    __syncthreads();
    if (threadIdx.x == 0) out[0] = (sm[0] + sm[1] + sm[2] + sm[3]) * (1.0f / (float)N_);
}

extern "C" void kernel_launch(void* const* d_in, const int* in_sizes, int n_in,
                              void* d_out, int out_size, void* d_ws, size_t ws_size,
                              hipStream_t stream) {
    (void)in_sizes; (void)n_in; (void)out_size; (void)ws_size;
    const float* Q   = (const float*)d_in[0];
    const float* K   = (const float*)d_in[1];
    const int* loc   = (const int*)d_in[2];
    const int* labels= (const int*)d_in[3];
    float* out = (float*)d_out;

    char* ws = (char*)d_ws;
    char* Kn    = ws;                                   // 3136*4096 = 12,845,056 B
    char* Qn    = ws + 12845056;                        // N_*128    =     524,288 B
    float* Ssum = (float*)(ws + 12845056 + 524288);     // N_*4
    float* T    = Ssum + N_;                            // N_*4

    prep_kernel<<<VSTRIPS_ + N_ / 4, 256, 0, stream>>>(K, Q, loc, Kn, Qn, Ssum);
    ce_main<<<dim3(16, NPHASE_), 256, 0, stream>>>(Qn, Kn, Ssum);
    term_kernel<<<N_ / 4, 256, 0, stream>>>(Qn, Kn, labels, Ssum, T);
    reduce_kernel<<<1, 256, 0, stream>>>(T, out);
}